// Round 4
// baseline (166.689 us; speedup 1.0000x reference)
//
#include <hip/hip_runtime.h>

#define N_VARS 50000
#define N_TX   200000
#define DSZ    32

#define EDGES_PER_BLOCK 200   // per 256-thread block: 800KB contiguous W
#define NBLOCKS (N_TX / EDGES_PER_BLOCK)   // 1000 blocks = 4000 waves

typedef float f32x4 __attribute__((ext_vector_type(4)));

// Fused: (1) out += theta via atomics (order-free vs edge atomics; out pre-zeroed
// by memsetAsync), (2) edge transforms. Block owns 200 contiguous edges; its 4
// waves round-robin pairs so the block reads a tight moving window of W.
__global__ __launch_bounds__(256)
void fused_transform_kernel(const float* __restrict__ theta,
                            const float* __restrict__ W,
                            const float* __restrict__ bia,
                            const int* __restrict__ src,
                            const int* __restrict__ tgt,
                            float* __restrict__ out) {
    const int lane = threadIdx.x & 63;
    const int w    = threadIdx.x >> 6;            // wave within block (0..3)
    const int base = blockIdx.x * EDGES_PER_BLOCK;

    // ---- residual init: out += theta (grid-stride, fire-and-forget atomics) ----
    {
        const int n = N_VARS * DSZ;
        const int stride = gridDim.x * blockDim.x;
        for (int i = blockIdx.x * blockDim.x + threadIdx.x; i < n; i += stride)
            atomicAdd(out + i, theta[i]);
    }

    // ---- edge transforms ----
    const int j0    = (lane & 7) << 2;  // this lane's 4-wide col slice
    const int g     = lane >> 3;        // row-group within the 8-row band
    const bool wr   = (lane & 7) < 4;   // writer lanes (one per (it,g))
    const int myIt  = lane & 3;
    const int myRow = myIt * 8 + g;     // output row this lane owns

    for (int p = w; p < EDGES_PER_BLOCK / 2; p += 4) {
        const int e = base + 2 * p;     // wave-uniform -> scalar id loads

        const int sA = src[e],     tA = tgt[e];
        const int sB = src[e + 1], tB = tgt[e + 1];

        const f32x4 xA = *reinterpret_cast<const f32x4*>(theta + (size_t)sA * DSZ + j0);
        const f32x4 xB = *reinterpret_cast<const f32x4*>(theta + (size_t)sB * DSZ + j0);

        const f32x4* WA = reinterpret_cast<const f32x4*>(W + (size_t)e * (DSZ * DSZ));
        const f32x4* WB = WA + 256;

        // 8 KiB in flight per pair — nontemporal: W has zero reuse
        const f32x4 a0 = __builtin_nontemporal_load(WA +   0 + lane);
        const f32x4 a1 = __builtin_nontemporal_load(WA +  64 + lane);
        const f32x4 a2 = __builtin_nontemporal_load(WA + 128 + lane);
        const f32x4 a3 = __builtin_nontemporal_load(WA + 192 + lane);
        const f32x4 c0 = __builtin_nontemporal_load(WB +   0 + lane);
        const f32x4 c1 = __builtin_nontemporal_load(WB +  64 + lane);
        const f32x4 c2 = __builtin_nontemporal_load(WB + 128 + lane);
        const f32x4 c3 = __builtin_nontemporal_load(WB + 192 + lane);

        const float biasA = __builtin_nontemporal_load(bia + (size_t)e * DSZ + myRow);
        const float biasB = __builtin_nontemporal_load(bia + (size_t)(e + 1) * DSZ + myRow);

        float pA0 = a0.x * xA.x + a0.y * xA.y + a0.z * xA.z + a0.w * xA.w;
        float pA1 = a1.x * xA.x + a1.y * xA.y + a1.z * xA.z + a1.w * xA.w;
        float pA2 = a2.x * xA.x + a2.y * xA.y + a2.z * xA.z + a2.w * xA.w;
        float pA3 = a3.x * xA.x + a3.y * xA.y + a3.z * xA.z + a3.w * xA.w;
        float pB0 = c0.x * xB.x + c0.y * xB.y + c0.z * xB.z + c0.w * xB.w;
        float pB1 = c1.x * xB.x + c1.y * xB.y + c1.z * xB.z + c1.w * xB.w;
        float pB2 = c2.x * xB.x + c2.y * xB.y + c2.z * xB.z + c2.w * xB.w;
        float pB3 = c3.x * xB.x + c3.y * xB.y + c3.z * xB.z + c3.w * xB.w;

        #pragma unroll
        for (int m = 1; m <= 4; m <<= 1) {
            pA0 += __shfl_xor(pA0, m); pA1 += __shfl_xor(pA1, m);
            pA2 += __shfl_xor(pA2, m); pA3 += __shfl_xor(pA3, m);
            pB0 += __shfl_xor(pB0, m); pB1 += __shfl_xor(pB1, m);
            pB2 += __shfl_xor(pB2, m); pB3 += __shfl_xor(pB3, m);
        }

        if (wr) {
            const float vA = (myIt == 0) ? pA0 : (myIt == 1) ? pA1 : (myIt == 2) ? pA2 : pA3;
            const float vB = (myIt == 0) ? pB0 : (myIt == 1) ? pB1 : (myIt == 2) ? pB2 : pB3;
            atomicAdd(out + (size_t)tA * DSZ + myRow, -(vA + biasA));
            atomicAdd(out + (size_t)tB * DSZ + myRow, -(vB + biasB));
        }
    }
}

extern "C" void kernel_launch(void* const* d_in, const int* in_sizes, int n_in,
                              void* d_out, int out_size, void* d_ws, size_t ws_size,
                              hipStream_t stream) {
    const float* theta = (const float*)d_in[0];
    const float* W     = (const float*)d_in[1];
    const float* b     = (const float*)d_in[2];
    const int*   src   = (const int*)d_in[3];
    const int*   tgt   = (const int*)d_in[4];
    float* out = (float*)d_out;

    // out = 0, then everything accumulates atomically (order-free)
    hipMemsetAsync(out, 0, (size_t)N_VARS * DSZ * sizeof(float), stream);

    fused_transform_kernel<<<NBLOCKS, 256, 0, stream>>>(theta, W, b, src, tgt, out);
}

// Round 5
// 155.539 us; speedup vs baseline: 1.0717x; 1.0717x over previous
//
#include <hip/hip_runtime.h>

#define N_VARS 50000
#define N_TX   200000
#define DSZ    32

#define NWAVES 4000                    // single resident batch (16 waves/CU x 256 CU)
#define NPAIRS (N_TX / 2)              // 100000
#define PAIRS_PER_WAVE (NPAIRS / NWAVES)   // 25, exact

typedef float f32x4 __attribute__((ext_vector_type(4)));

// out = theta (residual initialization), vectorized float4
__global__ void copy_theta_kernel(const float4* __restrict__ theta,
                                  float4* __restrict__ out, int n4) {
    int i = blockIdx.x * blockDim.x + threadIdx.x;
    int stride = gridDim.x * blockDim.x;
    for (; i < n4; i += stride) out[i] = theta[i];
}

// Pair-granularity grid-stride: wave w processes pairs {w, w+NWAVES, ...}.
// At any instant all 4000 waves read one contiguous 32MB sliding window of W.
// Lane l covers W flat float4 at lane*4 within each 1KiB quarter:
//   row i = it*8 + (l>>3), cols j0 = (l&7)*4.
// After the 3-step butterfly ALL 8 lanes of a group hold the row totals, so:
//   lanes (l&7)<4  write edge A, row (l&3)*8+(l>>3)
//   lanes (l&7)>=4 write edge B, same row mapping
// -> exactly one bias load and one atomicAdd per lane.
__global__ __launch_bounds__(256)
void transform_scatter_kernel(const float* __restrict__ theta,
                              const float* __restrict__ W,
                              const float* __restrict__ bia,
                              const int* __restrict__ src,
                              const int* __restrict__ tgt,
                              float* __restrict__ out) {
    const int lane = threadIdx.x & 63;
    const int wave = (blockIdx.x * blockDim.x + threadIdx.x) >> 6;

    const int j0     = (lane & 7) << 2;   // this lane's 4-wide col slice
    const int g      = lane >> 3;         // row-group within the 8-row band
    const int myRow  = (lane & 3) * 8 + g;
    const bool hiB   = (lane & 4) != 0;   // lanes that write edge B

    // prologue: ids for first pair
    int p  = wave;
    int sA = src[2 * p], sB = src[2 * p + 1];
    int tA = tgt[2 * p], tB = tgt[2 * p + 1];

    #pragma unroll 1
    for (int it = 0; it < PAIRS_PER_WAVE; ++it) {
        const int e = 2 * p;

        const f32x4 xA = *reinterpret_cast<const f32x4*>(theta + (size_t)sA * DSZ + j0);
        const f32x4 xB = *reinterpret_cast<const f32x4*>(theta + (size_t)sB * DSZ + j0);

        const f32x4* WA = reinterpret_cast<const f32x4*>(W + (size_t)e * (DSZ * DSZ));
        const f32x4* WB = WA + 256;

        // 8 KiB in flight — nontemporal: W has zero reuse, keep it out of L2
        const f32x4 a0 = __builtin_nontemporal_load(WA +   0 + lane);
        const f32x4 a1 = __builtin_nontemporal_load(WA +  64 + lane);
        const f32x4 a2 = __builtin_nontemporal_load(WA + 128 + lane);
        const f32x4 a3 = __builtin_nontemporal_load(WA + 192 + lane);
        const f32x4 c0 = __builtin_nontemporal_load(WB +   0 + lane);
        const f32x4 c1 = __builtin_nontemporal_load(WB +  64 + lane);
        const f32x4 c2 = __builtin_nontemporal_load(WB + 128 + lane);
        const f32x4 c3 = __builtin_nontemporal_load(WB + 192 + lane);

        // one bias element per lane (its own edge + row)
        const float biasv =
            __builtin_nontemporal_load(bia + ((size_t)e + (hiB ? 1 : 0)) * DSZ + myRow);

        // prefetch next pair's ids (uniform -> SGPR rotation)
        const int pn = p + NWAVES;
        const int pc = (it + 1 < PAIRS_PER_WAVE) ? pn : wave;  // clamp: avoid OOB
        const int sA2 = src[2 * pc], sB2 = src[2 * pc + 1];
        const int tA2 = tgt[2 * pc], tB2 = tgt[2 * pc + 1];

        float pA0 = a0.x * xA.x + a0.y * xA.y + a0.z * xA.z + a0.w * xA.w;
        float pA1 = a1.x * xA.x + a1.y * xA.y + a1.z * xA.z + a1.w * xA.w;
        float pA2 = a2.x * xA.x + a2.y * xA.y + a2.z * xA.z + a2.w * xA.w;
        float pA3 = a3.x * xA.x + a3.y * xA.y + a3.z * xA.z + a3.w * xA.w;
        float pB0 = c0.x * xB.x + c0.y * xB.y + c0.z * xB.z + c0.w * xB.w;
        float pB1 = c1.x * xB.x + c1.y * xB.y + c1.z * xB.z + c1.w * xB.w;
        float pB2 = c2.x * xB.x + c2.y * xB.y + c2.z * xB.z + c2.w * xB.w;
        float pB3 = c3.x * xB.x + c3.y * xB.y + c3.z * xB.z + c3.w * xB.w;

        #pragma unroll
        for (int m = 1; m <= 4; m <<= 1) {
            pA0 += __shfl_xor(pA0, m); pA1 += __shfl_xor(pA1, m);
            pA2 += __shfl_xor(pA2, m); pA3 += __shfl_xor(pA3, m);
            pB0 += __shfl_xor(pB0, m); pB1 += __shfl_xor(pB1, m);
            pB2 += __shfl_xor(pB2, m); pB3 += __shfl_xor(pB3, m);
        }

        // after butterfly every lane of the group holds all row totals:
        const int   r   = lane & 3;
        const float sA_ = (r == 0) ? pA0 : (r == 1) ? pA1 : (r == 2) ? pA2 : pA3;
        const float sB_ = (r == 0) ? pB0 : (r == 1) ? pB1 : (r == 2) ? pB2 : pB3;
        const float val = hiB ? sB_ : sA_;
        const int   te  = hiB ? tB : tA;

        atomicAdd(out + (size_t)te * DSZ + myRow, -(val + biasv));

        p = pn; sA = sA2; sB = sB2; tA = tA2; tB = tB2;
    }
}

extern "C" void kernel_launch(void* const* d_in, const int* in_sizes, int n_in,
                              void* d_out, int out_size, void* d_ws, size_t ws_size,
                              hipStream_t stream) {
    const float* theta = (const float*)d_in[0];
    const float* W     = (const float*)d_in[1];
    const float* b     = (const float*)d_in[2];
    const int*   src   = (const int*)d_in[3];
    const int*   tgt   = (const int*)d_in[4];
    float* out = (float*)d_out;

    // 1) out = theta
    const int n4 = (N_VARS * DSZ) / 4;
    copy_theta_kernel<<<1024, 256, 0, stream>>>((const float4*)theta, (float4*)out, n4);

    // 2) scatter transforms: 4000 waves, pair grid-stride (global sliding window)
    transform_scatter_kernel<<<NWAVES / 4, 256, 0, stream>>>(theta, W, b, src, tgt, out);
}